// Round 7
// baseline (13070.016 us; speedup 1.0000x reference)
//
#include <hip/hip_runtime.h>
#include <hip/hip_bf16.h>
#include <math.h>

// ---- problem dims ----
constexpr int NB   = 32;
constexpr int NS   = 256;
constexpr int NLC  = 16;
constexpr int NWD  = 256;
constexpr int NCD  = 124;
constexpr int NCO  = 32;
constexpr int NPOS = 36;
constexpr int NENR = 7;
constexpr int NH   = 512;
constexpr int NT   = 18;
constexpr int NIN0 = 331;
constexpr int NIN0P= 352;    // padded to x32 for BK=32
constexpr int NIN1 = 1024;
constexpr int NBS  = NB*NS;  // 8192
constexpr int NG4  = 4*NH;   // 2048
constexpr int NHID = 128;
constexpr int NCHUNK = 16;   // unit-chunks per dir (32 units each)

typedef __attribute__((ext_vector_type(8))) short short8v;
typedef __attribute__((ext_vector_type(4))) float f32x4;

__device__ __forceinline__ float sigmoidf_(float x){ return 1.0f/(1.0f+expf(-x)); }
__device__ __forceinline__ short f2bf(float f) {
    union { __hip_bfloat16 h; short s; } u;
    u.h = __float2bfloat16(f);
    return u.s;
}
__device__ __forceinline__ float bf2f(short s) {
    union { unsigned u; float f; } v;
    v.u = ((unsigned)(unsigned short)s) << 16;
    return v.f;
}
__device__ __forceinline__ unsigned packbf3(float v) {
    short hi = f2bf(v);
    short lo = f2bf(v - bf2f(hi));
    return ((unsigned)(unsigned short)hi << 16) | (unsigned short)lo;
}
// 8 packed u32 (elems k..k+7) -> hi/lo bf16 fragments
__device__ __forceinline__ void unpack8(const unsigned* w, short8v& hi, short8v& lo) {
    union U { short8v s; unsigned u[4]; } H, L;
    #pragma unroll
    for (int i = 0; i < 4; i++) {
        H.u[i] = (w[2*i+1] & 0xFFFF0000u) | (w[2*i] >> 16);
        L.u[i] = (w[2*i+1] << 16) | (w[2*i] & 0xFFFFu);
    }
    hi = H.s; lo = L.s;
}
// relaxed agent-scope ops (sc1 path, no cache maintenance) — proven in r6
__device__ __forceinline__ unsigned ld_sc1(const unsigned* p) {
    return __hip_atomic_load(p, __ATOMIC_RELAXED, __HIP_MEMORY_SCOPE_AGENT);
}
__device__ __forceinline__ unsigned long long ld64_sc1(const void* p) {
    return __hip_atomic_load((const unsigned long long*)p, __ATOMIC_RELAXED,
                             __HIP_MEMORY_SCOPE_AGENT);
}
__device__ __forceinline__ void st_sc1(unsigned* p, unsigned v) {
    __hip_atomic_store(p, v, __ATOMIC_RELAXED, __HIP_MEMORY_SCOPE_AGENT);
}

// ---------------- features: word embed + char CNN + concat + relu -> packed u32 ----
__global__ __launch_bounds__(128) void k_features(const int* __restrict__ x_word,
    const float* __restrict__ x_pos, const int* __restrict__ x_char,
    const float* __restrict__ x_enr, const float* __restrict__ wembW,
    const float* __restrict__ cembW, const float* __restrict__ cnnW,
    const float* __restrict__ cnnb, unsigned* __restrict__ xout)
{
    __shared__ float ce[NLC][NCD];
    __shared__ float cv[NCO][13];
    __shared__ float cpool[NCO];
    int n = blockIdx.x;
    int tid = threadIdx.x;
    for (int i = tid; i < NLC*NCD; i += 128) {
        int l = i / NCD, c = i % NCD;
        ce[l][c] = cembW[x_char[n*NLC + l]*NCD + c];
    }
    __syncthreads();
    for (int p = tid; p < NCO*12; p += 128) {
        int o = p & 31, t = p >> 5;
        const float* wr = cnnW + o*NCD*5;
        float acc = 0.f;
        for (int c = 0; c < NCD; c++) {
            #pragma unroll
            for (int k = 0; k < 5; k++) acc += ce[t+k][c] * wr[c*5+k];
        }
        cv[o][t] = acc;
    }
    __syncthreads();
    if (tid < NCO) {
        float m = cv[tid][0];
        #pragma unroll
        for (int t = 1; t < 12; t++) m = fmaxf(m, cv[tid][t]);
        cpool[tid] = m + cnnb[tid];
    }
    __syncthreads();
    int widx = x_word[n];
    unsigned* xr = xout + (size_t)n * NIN0P;
    for (int j = tid; j < NIN0P; j += 128) {
        float v;
        if (j < NWD)            v = wembW[(size_t)widx*NWD + j];
        else if (j < NWD+NPOS)  v = x_pos[n*NPOS + (j-NWD)];
        else if (j < NWD+NPOS+NCO) v = cpool[j-(NWD+NPOS)];
        else if (j < NIN0)      v = x_enr[n*NENR + (j-(NWD+NPOS+NCO))];
        else                    v = 0.f;   // K pad
        xr[j] = packbf3(fmaxf(v, 0.f));
    }
}

// ---------------- pack f32 weight [N][Ksrc] -> packed u32 [N][Kdst] (zero pad) ----
__global__ void k_pack_w(const float* __restrict__ W, unsigned* __restrict__ out,
                         int N, int Ksrc, int Kdst)
{
    int idx = blockIdx.x*256 + threadIdx.x;
    if (idx >= N*Kdst) return;
    int n = idx / Kdst, k = idx % Kdst;
    float v = (k < Ksrc) ? W[(size_t)n*Ksrc + k] : 0.f;
    out[idx] = packbf3(v);
}

// ---------------- bf16x3 MFMA GEMM: C[M,N] = A@W^T + bias ----------------
constexpr int TBK = 32;
constexpr int LSTR = 36;
__global__ __launch_bounds__(256, 2) void k_gemm_bf3(
    const unsigned* __restrict__ A, const unsigned* __restrict__ W,
    const float* __restrict__ bias, float* __restrict__ C,
    int M, int N, int K)
{
    __shared__ unsigned Asl[128*LSTR];
    __shared__ unsigned Bsl[128*LSTR];
    int bm = blockIdx.x*128, bn = blockIdx.y*128;
    int tid = threadIdx.x;
    int l = tid & 63, wv = tid >> 6;
    int wm = wv >> 1, wn = wv & 1;
    int lr = l & 15, lk = l >> 4;

    f32x4 acc[4][4];
    #pragma unroll
    for (int i = 0; i < 4; i++)
        #pragma unroll
        for (int j = 0; j < 4; j++) acc[i][j] = (f32x4){0.f,0.f,0.f,0.f};

    uint4 ra[4], rb[4];
    int KT = K / TBK;
    #pragma unroll
    for (int i = 0; i < 4; i++) {
        int idx = i*256 + tid, row = idx >> 3, c4 = (idx & 7)*4;
        ra[i] = *(const uint4*)(A + (size_t)(bm+row)*K + c4);
        rb[i] = *(const uint4*)(W + (size_t)(bn+row)*K + c4);
    }
    for (int kt = 0; kt < KT; kt++) {
        #pragma unroll
        for (int i = 0; i < 4; i++) {
            int idx = i*256 + tid, row = idx >> 3, c4 = (idx & 7)*4;
            *(uint4*)&Asl[row*LSTR + c4] = ra[i];
            *(uint4*)&Bsl[row*LSTR + c4] = rb[i];
        }
        __syncthreads();
        if (kt+1 < KT) {
            #pragma unroll
            for (int i = 0; i < 4; i++) {
                int idx = i*256 + tid, row = idx >> 3, c4 = (idx & 7)*4;
                ra[i] = *(const uint4*)(A + (size_t)(bm+row)*K + (kt+1)*TBK + c4);
                rb[i] = *(const uint4*)(W + (size_t)(bn+row)*K + (kt+1)*TBK + c4);
            }
        }
        short8v Ah[4], Al_[4], Bh[4], Bl[4];
        #pragma unroll
        for (int f = 0; f < 4; f++) {
            unsigned w8[8];
            int rowA = wm*64 + f*16 + lr;
            *(uint4*)&w8[0] = *(const uint4*)&Asl[rowA*LSTR + lk*8];
            *(uint4*)&w8[4] = *(const uint4*)&Asl[rowA*LSTR + lk*8 + 4];
            unpack8(w8, Ah[f], Al_[f]);
            int rowB = wn*64 + f*16 + lr;
            *(uint4*)&w8[0] = *(const uint4*)&Bsl[rowB*LSTR + lk*8];
            *(uint4*)&w8[4] = *(const uint4*)&Bsl[rowB*LSTR + lk*8 + 4];
            unpack8(w8, Bh[f], Bl[f]);
        }
        #pragma unroll
        for (int i = 0; i < 4; i++)
            #pragma unroll
            for (int j = 0; j < 4; j++) {
                acc[i][j] = __builtin_amdgcn_mfma_f32_16x16x32_bf16(Ah[i],  Bh[j], acc[i][j], 0, 0, 0);
                acc[i][j] = __builtin_amdgcn_mfma_f32_16x16x32_bf16(Al_[i], Bh[j], acc[i][j], 0, 0, 0);
                acc[i][j] = __builtin_amdgcn_mfma_f32_16x16x32_bf16(Ah[i],  Bl[j], acc[i][j], 0, 0, 0);
            }
        __syncthreads();
    }
    #pragma unroll
    for (int i = 0; i < 4; i++) {
        int m0 = bm + wm*64 + i*16 + lk*4;
        #pragma unroll
        for (int j = 0; j < 4; j++) {
            int n0 = bn + wn*64 + j*16 + lr;
            float bv = bias[n0];
            #pragma unroll
            for (int q = 0; q < 4; q++)
                C[(size_t)(m0+q)*N + n0] = acc[i][j][q] + bv;
        }
    }
}

// ---------------- persistent LSTM layer: 16 chunks x 2 dirs, 256 thr ----------
// 4 waves = 4 gates, full K=512 per wave (no split-K). 1 wave/SIMD -> 512-VGPR
// budget keeps the 256 weight VGPRs resident (r6's 512-thr variant spilled).
// Direct sc1->register A-fragments (no LDS staging), per-wave release flags,
// ONE barrier per step (zsh handoff). Exchange discipline proven in r6:
// relaxed agent-scope (sc1) everywhere, per-wave s_waitcnt vmcnt(0) before flag.
__global__ __launch_bounds__(256, 1) void k_lstm_layer(
    const float* __restrict__ zx_f, const float* __restrict__ zx_b,
    const float* __restrict__ Whh_f, const float* __restrict__ Whh_b,
    unsigned* __restrict__ hpack, unsigned* __restrict__ hbf,
    unsigned* __restrict__ flags)
{
    int chunk = blockIdx.x;        // 0..15 (32 hidden units each)
    int dir   = blockIdx.y;
    int tid = threadIdx.x;
    int wv = tid >> 6, l = tid & 63;
    int g  = wv;                   // wave = gate
    int lr = l & 15, lk = l >> 4;
    const float* zx  = dir ? zx_b  : zx_f;
    const float* Whh = dir ? Whh_b : Whh_f;
    unsigned* hb = hbf + (size_t)dir * (2*NB*NH);     // [slot][b][k] packed u32
    unsigned* flag = flags + (size_t)dir * (NCHUNK*4);  // dense: [chunk][wave]

    // ---- preload Whh slice: gate g, units chunk*32 + uh*16 + lr, all K ----
    short8v bwh[2][16], bwl[2][16];
    #pragma unroll
    for (int uh = 0; uh < 2; uh++) {
        const float* wrow = Whh + ((size_t)(g*NH + chunk*32 + uh*16 + lr))*NH + lk*8;
        #pragma unroll
        for (int kt = 0; kt < 16; kt++) {
            float u[8];
            *(float4*)&u[0] = *(const float4*)(wrow + kt*32);
            *(float4*)&u[4] = *(const float4*)(wrow + kt*32 + 4);
            short8v sh, sl;
            #pragma unroll
            for (int j = 0; j < 8; j++) {
                short hi = f2bf(u[j]);
                sh[j] = hi;
                sl[j] = f2bf(u[j] - bf2f(hi));
            }
            bwh[uh][kt] = sh; bwl[uh][kt] = sl;
        }
    }

    __shared__ float zsh[4][32][33];   // [gate][batch][unit(+pad)]
    float cs0 = 0.f, cs1 = 0.f, cs2 = 0.f, cs3 = 0.f;   // cell state, 4 cells/thread

    for (int t = 0; t < NS; t++) {
        int t_eff = dir ? (NS-1-t) : t;

        // ---- prefetch zx into regs (independent of the flag) ----
        float pz[4][4];
        #pragma unroll
        for (int cc = 0; cc < 4; cc++) {
            int cell = tid + cc*256, b = cell >> 5, u = cell & 31;
            const float* zr = zx + ((size_t)(b*NS + t_eff))*NG4 + chunk*32 + u;
            #pragma unroll
            for (int g2 = 0; g2 < 4; g2++) pz[cc][g2] = zr[g2*NH];
        }

        // accumulators: [bh][uh] main + cross (merged al*wh and ah*wl chains)
        f32x4 am00={0,0,0,0}, am01={0,0,0,0}, am10={0,0,0,0}, am11={0,0,0,0};
        f32x4 ac00={0,0,0,0}, ac01={0,0,0,0}, ac10={0,0,0,0}, ac11={0,0,0,0};

        if (t > 0) {
            // ---- poll all 64 per-wave flags (2 per lane via u64) ----
            {
                const unsigned long long* fp =
                    (const unsigned long long*)flag + (l & 31);
                unsigned tv = (unsigned)t;
                unsigned long long v;
                do { v = ld64_sc1(fp); }
                while (!__all(((unsigned)v >= tv) && ((unsigned)(v>>32) >= tv)));
                asm volatile("" ::: "memory");
            }
            // ---- direct sc1 A-fragment loads, ping-pong pipelined ----
            const unsigned* hp = hb + ((t-1)&1)*(NB*NH);
            const unsigned* base0 = hp + lr*NH      + lk*8;   // batches 0..15
            const unsigned* base1 = hp + (16+lr)*NH + lk*8;   // batches 16..31
            unsigned long long q[2][2][4];
            #pragma unroll
            for (int i = 0; i < 4; i++) {
                q[0][0][i] = ld64_sc1(base0 + 2*i);
                q[0][1][i] = ld64_sc1(base1 + 2*i);
            }
            #pragma unroll
            for (int kt = 0; kt < 16; kt++) {
                const int cur = kt & 1, nxt = cur ^ 1;
                if (kt < 15) {
                    #pragma unroll
                    for (int i = 0; i < 4; i++) {
                        q[nxt][0][i] = ld64_sc1(base0 + (kt+1)*32 + 2*i);
                        q[nxt][1][i] = ld64_sc1(base1 + (kt+1)*32 + 2*i);
                    }
                }
                short8v ah0, al0, ah1, al1;
                {
                    unsigned w8[8];
                    #pragma unroll
                    for (int i = 0; i < 4; i++) {
                        w8[2*i]   = (unsigned)q[cur][0][i];
                        w8[2*i+1] = (unsigned)(q[cur][0][i] >> 32);
                    }
                    unpack8(w8, ah0, al0);
                    #pragma unroll
                    for (int i = 0; i < 4; i++) {
                        w8[2*i]   = (unsigned)q[cur][1][i];
                        w8[2*i+1] = (unsigned)(q[cur][1][i] >> 32);
                    }
                    unpack8(w8, ah1, al1);
                }
                am00 = __builtin_amdgcn_mfma_f32_16x16x32_bf16(ah0, bwh[0][kt], am00, 0, 0, 0);
                am01 = __builtin_amdgcn_mfma_f32_16x16x32_bf16(ah0, bwh[1][kt], am01, 0, 0, 0);
                am10 = __builtin_amdgcn_mfma_f32_16x16x32_bf16(ah1, bwh[0][kt], am10, 0, 0, 0);
                am11 = __builtin_amdgcn_mfma_f32_16x16x32_bf16(ah1, bwh[1][kt], am11, 0, 0, 0);
                ac00 = __builtin_amdgcn_mfma_f32_16x16x32_bf16(al0, bwh[0][kt], ac00, 0, 0, 0);
                ac00 = __builtin_amdgcn_mfma_f32_16x16x32_bf16(ah0, bwl[0][kt], ac00, 0, 0, 0);
                ac01 = __builtin_amdgcn_mfma_f32_16x16x32_bf16(al0, bwh[1][kt], ac01, 0, 0, 0);
                ac01 = __builtin_amdgcn_mfma_f32_16x16x32_bf16(ah0, bwl[1][kt], ac01, 0, 0, 0);
                ac10 = __builtin_amdgcn_mfma_f32_16x16x32_bf16(al1, bwh[0][kt], ac10, 0, 0, 0);
                ac10 = __builtin_amdgcn_mfma_f32_16x16x32_bf16(ah1, bwl[0][kt], ac10, 0, 0, 0);
                ac11 = __builtin_amdgcn_mfma_f32_16x16x32_bf16(al1, bwh[1][kt], ac11, 0, 0, 0);
                ac11 = __builtin_amdgcn_mfma_f32_16x16x32_bf16(ah1, bwl[1][kt], ac11, 0, 0, 0);
            }
        }
        // C layout: col=lane&15 -> unit uh*16+lr, row=(lane>>4)*4+j -> batch
        #pragma unroll
        for (int j = 0; j < 4; j++) {
            zsh[g][lk*4+j][lr]       = am00[j] + ac00[j];
            zsh[g][lk*4+j][16+lr]    = am01[j] + ac01[j];
            zsh[g][16+lk*4+j][lr]    = am10[j] + ac10[j];
            zsh[g][16+lk*4+j][16+lr] = am11[j] + ac11[j];
        }
        __syncthreads();   // the one barrier per step: zsh handoff

        // ---- epilogue: 1024 cells / 256 threads (4 each) ----
        unsigned hq[4];
        #pragma unroll
        for (int cc = 0; cc < 4; cc++) {
            int cell = tid + cc*256, b = cell >> 5, u = cell & 31;
            float zi = pz[cc][0] + zsh[0][b][u];
            float zf = pz[cc][1] + zsh[1][b][u];
            float zg = pz[cc][2] + zsh[2][b][u];
            float zo = pz[cc][3] + zsh[3][b][u];
            float cold = (cc==0) ? cs0 : (cc==1) ? cs1 : (cc==2) ? cs2 : cs3;
            float cn = sigmoidf_(zf)*cold + sigmoidf_(zi)*tanhf(zg);
            float hn = sigmoidf_(zo)*tanhf(cn);
            if (cc==0) cs0 = cn; else if (cc==1) cs1 = cn; else if (cc==2) cs2 = cn; else cs3 = cn;
            hq[cc] = packbf3(hn);
            st_sc1(&hb[(size_t)(t&1)*(NB*NH) + b*NH + chunk*32 + u], hq[cc]);
        }
        // per-wave release: own stores acked, then own flag
        asm volatile("s_waitcnt vmcnt(0)" ::: "memory");
        if (l == 0) st_sc1(&flag[chunk*4 + wv], (unsigned)(t+1));
        // packed h for downstream GEMMs (off critical path)
        #pragma unroll
        for (int cc = 0; cc < 4; cc++) {
            int cell = tid + cc*256, b = cell >> 5, u = cell & 31;
            hpack[((size_t)(b*NS + t_eff))*NIN1 + dir*NH + chunk*32 + u] = hq[cc];
        }
    }
}

// ---------------- emissions: em = hid1 @ lin2W^T + b2 ----------------
__global__ __launch_bounds__(256) void k_lin2(const float* __restrict__ hid,
    const float* __restrict__ W2, const float* __restrict__ b2, float* __restrict__ em)
{
    int flat = blockIdx.x*256 + threadIdx.x;
    if (flat >= NBS*NT) return;
    int m = flat / NT, j = flat % NT;
    const float* hr = hid + (size_t)m*NHID;
    const float* wr = W2 + j*NHID;
    float acc = b2[j];
    #pragma unroll 8
    for (int k = 0; k < NHID; k += 4) {
        float4 h4 = *(const float4*)(hr+k);
        float4 w4 = *(const float4*)(wr+k);
        acc += h4.x*w4.x + h4.y*w4.y + h4.z*w4.z + h4.w*w4.w;
    }
    em[flat] = acc;
}

// ---------------- viterbi decode (one wave per batch item) ----------------
__global__ __launch_bounds__(64) void k_viterbi(const float* __restrict__ em,
    const float* __restrict__ start, const float* __restrict__ endv,
    const float* __restrict__ trans, float* __restrict__ dec)
{
    __shared__ float sc[NT];
    __shared__ float tr[NT][NT];
    __shared__ unsigned char hist[NS][NT];
    int b = blockIdx.x, tid = threadIdx.x;
    for (int i = tid; i < NT*NT; i += 64) tr[i/NT][i%NT] = trans[i];
    if (tid < NT) sc[tid] = start[tid] + em[((size_t)b*NS)*NT + tid];
    __syncthreads();
    for (int t = 1; t < NS; t++) {
        float best = -1e30f; int bi = 0;
        if (tid < NT) {
            for (int i = 0; i < NT; i++) {
                float v = sc[i] + tr[i][tid];
                if (v > best) { best = v; bi = i; }
            }
            hist[t][tid] = (unsigned char)bi;
            best += em[((size_t)b*NS + t)*NT + tid];
        }
        __syncthreads();
        if (tid < NT) sc[tid] = best;
        __syncthreads();
    }
    if (tid == 0) {
        float bv = sc[0] + endv[0]; int tag = 0;
        for (int j = 1; j < NT; j++) { float v = sc[j] + endv[j]; if (v > bv) { bv = v; tag = j; } }
        dec[b*NS + NS-1] = (float)tag;
        for (int t = NS-1; t >= 1; t--) { tag = hist[t][tag]; dec[b*NS + t-1] = (float)tag; }
    }
}

// ---------------- CRF NLL (mask is all ones) ----------------
__global__ __launch_bounds__(64) void k_nll(const float* __restrict__ em,
    const int* __restrict__ tags, const float* __restrict__ start,
    const float* __restrict__ endv, const float* __restrict__ trans,
    float* __restrict__ partial)
{
    __shared__ float sc[NT];
    __shared__ float tr[NT][NT];
    int b = blockIdx.x, tid = threadIdx.x;
    for (int i = tid; i < NT*NT; i += 64) tr[i/NT][i%NT] = trans[i];
    if (tid < NT) sc[tid] = start[tid] + em[((size_t)b*NS)*NT + tid];
    __syncthreads();
    for (int t = 1; t < NS; t++) {
        float nv = 0.f;
        if (tid < NT) {
            float m = -1e30f;
            for (int i = 0; i < NT; i++) m = fmaxf(m, sc[i] + tr[i][tid]);
            float s = 0.f;
            for (int i = 0; i < NT; i++) s += expf(sc[i] + tr[i][tid] - m);
            nv = m + logf(s) + em[((size_t)b*NS + t)*NT + tid];
        }
        __syncthreads();
        if (tid < NT) sc[tid] = nv;
        __syncthreads();
    }
    if (tid == 0) {
        float m = -1e30f;
        for (int j = 0; j < NT; j++) m = fmaxf(m, sc[j] + endv[j]);
        float s = 0.f;
        for (int j = 0; j < NT; j++) s += expf(sc[j] + endv[j] - m);
        float logZ = m + logf(s);
        const int* tg = tags + b*NS;
        float num = start[tg[0]] + em[((size_t)b*NS)*NT + tg[0]];
        for (int t = 1; t < NS; t++)
            num += tr[tg[t-1]][tg[t]] + em[((size_t)b*NS + t)*NT + tg[t]];
        num += endv[tg[NS-1]];
        partial[b] = -(num - logZ);
    }
}

__global__ void k_loss_final(const float* __restrict__ partial, float* __restrict__ loss)
{
    if (threadIdx.x == 0 && blockIdx.x == 0) {
        float s = 0.f;
        for (int b = 0; b < NB; b++) s += partial[b];
        *loss = s / (float)(NB*NS);
    }
}

extern "C" void kernel_launch(void* const* d_in, const int* in_sizes, int n_in,
                              void* d_out, int out_size, void* d_ws, size_t ws_size,
                              hipStream_t stream)
{
    const int*   x_word = (const int*)d_in[0];
    const float* x_pos  = (const float*)d_in[1];
    const int*   x_char = (const int*)d_in[2];
    const float* x_enr  = (const float*)d_in[3];
    const int*   y_word = (const int*)d_in[5];
    const float* wembW  = (const float*)d_in[6];
    const float* cembW  = (const float*)d_in[7];
    const float* cnnW   = (const float*)d_in[8];
    const float* cnnb   = (const float*)d_in[9];
    const float* lin1W  = (const float*)d_in[10];
    const float* lin1b  = (const float*)d_in[11];
    const float* lin2W  = (const float*)d_in[12];
    const float* lin2b  = (const float*)d_in[13];
    const float* crf_s  = (const float*)d_in[14];
    const float* crf_e  = (const float*)d_in[15];
    const float* crf_tr = (const float*)d_in[16];
    const float* l0f_Wih = (const float*)d_in[17];
    const float* l0f_Whh = (const float*)d_in[18];
    const float* l0f_b   = (const float*)d_in[19];
    const float* l0b_Wih = (const float*)d_in[20];
    const float* l0b_Whh = (const float*)d_in[21];
    const float* l0b_b   = (const float*)d_in[22];
    const float* l1f_Wih = (const float*)d_in[23];
    const float* l1f_Whh = (const float*)d_in[24];
    const float* l1f_b   = (const float*)d_in[25];
    const float* l1b_Wih = (const float*)d_in[26];
    const float* l1b_Whh = (const float*)d_in[27];
    const float* l1b_b   = (const float*)d_in[28];

    unsigned* ws = (unsigned*)d_ws;
    size_t off = 0;
    unsigned* xwp  = ws + off; off += (size_t)NBS*NIN0P;
    unsigned* w0fp = ws + off; off += (size_t)NG4*NIN0P;
    unsigned* w0bp = ws + off; off += (size_t)NG4*NIN0P;
    unsigned* w1fp = ws + off; off += (size_t)NG4*NIN1;
    unsigned* w1bp = ws + off; off += (size_t)NG4*NIN1;
    unsigned* wl1p = ws + off; off += (size_t)NHID*NIN1;
    float*    zxf  = (float*)(ws + off); off += (size_t)NBS*NG4;
    float*    zxb  = (float*)(ws + off); off += (size_t)NBS*NG4;
    unsigned* h0p  = ws + off; off += (size_t)NBS*NIN1;
    unsigned* h1p  = ws + off; off += (size_t)NBS*NIN1;
    float*    hid1 = (float*)(ws + off); off += (size_t)NBS*NHID;
    float*    partial = (float*)(ws + off); off += 64;
    unsigned* hbf  = ws + off; off += (size_t)2*2*NB*NH;
    unsigned* flags= ws + off; off += (size_t)2*NCHUNK*4;

    float* em_out   = (float*)d_out;
    float* dec_out  = em_out + (size_t)NBS*NT;
    float* loss_out = dec_out + NBS;

    // 1. pack weights
    k_pack_w<<<(NG4*NIN0P+255)/256, 256, 0, stream>>>(l0f_Wih, w0fp, NG4, NIN0, NIN0P);
    k_pack_w<<<(NG4*NIN0P+255)/256, 256, 0, stream>>>(l0b_Wih, w0bp, NG4, NIN0, NIN0P);
    k_pack_w<<<(NG4*NIN1+255)/256, 256, 0, stream>>>(l1f_Wih, w1fp, NG4, NIN1, NIN1);
    k_pack_w<<<(NG4*NIN1+255)/256, 256, 0, stream>>>(l1b_Wih, w1bp, NG4, NIN1, NIN1);
    k_pack_w<<<(NHID*NIN1+255)/256, 256, 0, stream>>>(lin1W, wl1p, NHID, NIN1, NIN1);
    // 2. features (packed)
    k_features<<<NBS, 128, 0, stream>>>(x_word, x_pos, x_char, x_enr, wembW, cembW, cnnW, cnnb, xwp);
    // 3. layer-0 input projections
    k_gemm_bf3<<<dim3(NBS/128, NG4/128), 256, 0, stream>>>(xwp, w0fp, l0f_b, zxf, NBS, NG4, NIN0P);
    k_gemm_bf3<<<dim3(NBS/128, NG4/128), 256, 0, stream>>>(xwp, w0bp, l0b_b, zxb, NBS, NG4, NIN0P);
    // 4. layer-0 recurrence
    hipMemsetAsync(flags, 0, (size_t)2*NCHUNK*4*sizeof(unsigned), stream);
    k_lstm_layer<<<dim3(NCHUNK, 2), 256, 0, stream>>>(zxf, zxb, l0f_Whh, l0b_Whh, h0p, hbf, flags);
    // 5. layer-1 input projections
    k_gemm_bf3<<<dim3(NBS/128, NG4/128), 256, 0, stream>>>(h0p, w1fp, l1f_b, zxf, NBS, NG4, NIN1);
    k_gemm_bf3<<<dim3(NBS/128, NG4/128), 256, 0, stream>>>(h0p, w1bp, l1b_b, zxb, NBS, NG4, NIN1);
    // 6. layer-1 recurrence
    hipMemsetAsync(flags, 0, (size_t)2*NCHUNK*4*sizeof(unsigned), stream);
    k_lstm_layer<<<dim3(NCHUNK, 2), 256, 0, stream>>>(zxf, zxb, l1f_Whh, l1b_Whh, h1p, hbf, flags);
    // 7. head
    k_gemm_bf3<<<dim3(NBS/128, NHID/128), 256, 0, stream>>>(h1p, wl1p, lin1b, hid1, NBS, NHID, NIN1);
    k_lin2<<<(NBS*NT+255)/256, 256, 0, stream>>>(hid1, lin2W, lin2b, em_out);
    // 8. CRF
    k_viterbi<<<NB, 64, 0, stream>>>(em_out, crf_s, crf_e, crf_tr, dec_out);
    k_nll<<<NB, 64, 0, stream>>>(em_out, y_word, crf_s, crf_e, crf_tr, partial);
    k_loss_final<<<1, 64, 0, stream>>>(partial, loss_out);
}

// Round 8
// 6573.933 us; speedup vs baseline: 1.9882x; 1.9882x over previous
//
#include <hip/hip_runtime.h>
#include <hip/hip_bf16.h>
#include <math.h>

// ---- problem dims ----
constexpr int NB   = 32;
constexpr int NS   = 256;
constexpr int NLC  = 16;
constexpr int NWD  = 256;
constexpr int NCD  = 124;
constexpr int NCO  = 32;
constexpr int NPOS = 36;
constexpr int NENR = 7;
constexpr int NH   = 512;
constexpr int NT   = 18;
constexpr int NIN0 = 331;
constexpr int NIN0P= 352;    // padded to x32 for BK=32
constexpr int NIN1 = 1024;
constexpr int NBS  = NB*NS;  // 8192
constexpr int NG4  = 4*NH;   // 2048
constexpr int NHID = 128;
constexpr int NCHUNK = 16;   // unit-chunks per dir (32 units each)

typedef __attribute__((ext_vector_type(8))) short short8v;
typedef __attribute__((ext_vector_type(4))) float f32x4;

__device__ __forceinline__ float sigmoidf_(float x){ return 1.0f/(1.0f+expf(-x)); }
__device__ __forceinline__ short f2bf(float f) {
    union { __hip_bfloat16 h; short s; } u;
    u.h = __float2bfloat16(f);
    return u.s;
}
__device__ __forceinline__ float bf2f(short s) {
    union { unsigned u; float f; } v;
    v.u = ((unsigned)(unsigned short)s) << 16;
    return v.f;
}
__device__ __forceinline__ unsigned packbf3(float v) {
    short hi = f2bf(v);
    short lo = f2bf(v - bf2f(hi));
    return ((unsigned)(unsigned short)hi << 16) | (unsigned short)lo;
}
// 8 packed u32 (elems k..k+7) -> hi/lo bf16 fragments
__device__ __forceinline__ void unpack8(const unsigned* w, short8v& hi, short8v& lo) {
    union U { short8v s; unsigned u[4]; } H, L;
    #pragma unroll
    for (int i = 0; i < 4; i++) {
        H.u[i] = (w[2*i+1] & 0xFFFF0000u) | (w[2*i] >> 16);
        L.u[i] = (w[2*i+1] << 16) | (w[2*i] & 0xFFFFu);
    }
    hi = H.s; lo = L.s;
}
// relaxed agent-scope ops (sc1 path, no cache maintenance) — proven in r6
__device__ __forceinline__ unsigned ld_sc1(const unsigned* p) {
    return __hip_atomic_load(p, __ATOMIC_RELAXED, __HIP_MEMORY_SCOPE_AGENT);
}
__device__ __forceinline__ unsigned long long ld64_sc1(const void* p) {
    return __hip_atomic_load((const unsigned long long*)p, __ATOMIC_RELAXED,
                             __HIP_MEMORY_SCOPE_AGENT);
}
__device__ __forceinline__ void st_sc1(unsigned* p, unsigned v) {
    __hip_atomic_store(p, v, __ATOMIC_RELAXED, __HIP_MEMORY_SCOPE_AGENT);
}

// ---------------- features: word embed + char CNN + concat + relu -> packed u32 ----
__global__ __launch_bounds__(128) void k_features(const int* __restrict__ x_word,
    const float* __restrict__ x_pos, const int* __restrict__ x_char,
    const float* __restrict__ x_enr, const float* __restrict__ wembW,
    const float* __restrict__ cembW, const float* __restrict__ cnnW,
    const float* __restrict__ cnnb, unsigned* __restrict__ xout)
{
    __shared__ float ce[NLC][NCD];
    __shared__ float cv[NCO][13];
    __shared__ float cpool[NCO];
    int n = blockIdx.x;
    int tid = threadIdx.x;
    for (int i = tid; i < NLC*NCD; i += 128) {
        int l = i / NCD, c = i % NCD;
        ce[l][c] = cembW[x_char[n*NLC + l]*NCD + c];
    }
    __syncthreads();
    for (int p = tid; p < NCO*12; p += 128) {
        int o = p & 31, t = p >> 5;
        const float* wr = cnnW + o*NCD*5;
        float acc = 0.f;
        for (int c = 0; c < NCD; c++) {
            #pragma unroll
            for (int k = 0; k < 5; k++) acc += ce[t+k][c] * wr[c*5+k];
        }
        cv[o][t] = acc;
    }
    __syncthreads();
    if (tid < NCO) {
        float m = cv[tid][0];
        #pragma unroll
        for (int t = 1; t < 12; t++) m = fmaxf(m, cv[tid][t]);
        cpool[tid] = m + cnnb[tid];
    }
    __syncthreads();
    int widx = x_word[n];
    unsigned* xr = xout + (size_t)n * NIN0P;
    for (int j = tid; j < NIN0P; j += 128) {
        float v;
        if (j < NWD)            v = wembW[(size_t)widx*NWD + j];
        else if (j < NWD+NPOS)  v = x_pos[n*NPOS + (j-NWD)];
        else if (j < NWD+NPOS+NCO) v = cpool[j-(NWD+NPOS)];
        else if (j < NIN0)      v = x_enr[n*NENR + (j-(NWD+NPOS+NCO))];
        else                    v = 0.f;   // K pad
        xr[j] = packbf3(fmaxf(v, 0.f));
    }
}

// ---------------- pack f32 weight [N][Ksrc] -> packed u32 [N][Kdst] (zero pad) ----
__global__ void k_pack_w(const float* __restrict__ W, unsigned* __restrict__ out,
                         int N, int Ksrc, int Kdst)
{
    int idx = blockIdx.x*256 + threadIdx.x;
    if (idx >= N*Kdst) return;
    int n = idx / Kdst, k = idx % Kdst;
    float v = (k < Ksrc) ? W[(size_t)n*Ksrc + k] : 0.f;
    out[idx] = packbf3(v);
}

// ---------------- bf16x3 MFMA GEMM: C[M,N] = A@W^T + bias ----------------
constexpr int TBK = 32;
constexpr int LSTR = 36;
__global__ __launch_bounds__(256, 2) void k_gemm_bf3(
    const unsigned* __restrict__ A, const unsigned* __restrict__ W,
    const float* __restrict__ bias, float* __restrict__ C,
    int M, int N, int K)
{
    __shared__ unsigned Asl[128*LSTR];
    __shared__ unsigned Bsl[128*LSTR];
    int bm = blockIdx.x*128, bn = blockIdx.y*128;
    int tid = threadIdx.x;
    int l = tid & 63, wv = tid >> 6;
    int wm = wv >> 1, wn = wv & 1;
    int lr = l & 15, lk = l >> 4;

    f32x4 acc[4][4];
    #pragma unroll
    for (int i = 0; i < 4; i++)
        #pragma unroll
        for (int j = 0; j < 4; j++) acc[i][j] = (f32x4){0.f,0.f,0.f,0.f};

    uint4 ra[4], rb[4];
    int KT = K / TBK;
    #pragma unroll
    for (int i = 0; i < 4; i++) {
        int idx = i*256 + tid, row = idx >> 3, c4 = (idx & 7)*4;
        ra[i] = *(const uint4*)(A + (size_t)(bm+row)*K + c4);
        rb[i] = *(const uint4*)(W + (size_t)(bn+row)*K + c4);
    }
    for (int kt = 0; kt < KT; kt++) {
        #pragma unroll
        for (int i = 0; i < 4; i++) {
            int idx = i*256 + tid, row = idx >> 3, c4 = (idx & 7)*4;
            *(uint4*)&Asl[row*LSTR + c4] = ra[i];
            *(uint4*)&Bsl[row*LSTR + c4] = rb[i];
        }
        __syncthreads();
        if (kt+1 < KT) {
            #pragma unroll
            for (int i = 0; i < 4; i++) {
                int idx = i*256 + tid, row = idx >> 3, c4 = (idx & 7)*4;
                ra[i] = *(const uint4*)(A + (size_t)(bm+row)*K + (kt+1)*TBK + c4);
                rb[i] = *(const uint4*)(W + (size_t)(bn+row)*K + (kt+1)*TBK + c4);
            }
        }
        short8v Ah[4], Al_[4], Bh[4], Bl[4];
        #pragma unroll
        for (int f = 0; f < 4; f++) {
            unsigned w8[8];
            int rowA = wm*64 + f*16 + lr;
            *(uint4*)&w8[0] = *(const uint4*)&Asl[rowA*LSTR + lk*8];
            *(uint4*)&w8[4] = *(const uint4*)&Asl[rowA*LSTR + lk*8 + 4];
            unpack8(w8, Ah[f], Al_[f]);
            int rowB = wn*64 + f*16 + lr;
            *(uint4*)&w8[0] = *(const uint4*)&Bsl[rowB*LSTR + lk*8];
            *(uint4*)&w8[4] = *(const uint4*)&Bsl[rowB*LSTR + lk*8 + 4];
            unpack8(w8, Bh[f], Bl[f]);
        }
        #pragma unroll
        for (int i = 0; i < 4; i++)
            #pragma unroll
            for (int j = 0; j < 4; j++) {
                acc[i][j] = __builtin_amdgcn_mfma_f32_16x16x32_bf16(Ah[i],  Bh[j], acc[i][j], 0, 0, 0);
                acc[i][j] = __builtin_amdgcn_mfma_f32_16x16x32_bf16(Al_[i], Bh[j], acc[i][j], 0, 0, 0);
                acc[i][j] = __builtin_amdgcn_mfma_f32_16x16x32_bf16(Ah[i],  Bl[j], acc[i][j], 0, 0, 0);
            }
        __syncthreads();
    }
    #pragma unroll
    for (int i = 0; i < 4; i++) {
        int m0 = bm + wm*64 + i*16 + lk*4;
        #pragma unroll
        for (int j = 0; j < 4; j++) {
            int n0 = bn + wn*64 + j*16 + lr;
            float bv = bias[n0];
            #pragma unroll
            for (int q = 0; q < 4; q++)
                C[(size_t)(m0+q)*N + n0] = acc[i][j][q] + bv;
        }
    }
}

// ---------------- persistent LSTM layer: 16 chunks x 2 dirs, 256 thr ----------
// 4 waves = 4 gates, full K=512 per wave; launch_bounds(256,1) -> 512-VGPR
// budget keeps 128 weight VGPRs resident (r7-proven; r6's 512-thr spilled).
// Exchange (r6-proven): relaxed agent-scope (sc1) everywhere, coalesced BURST
// stage hb->LDS (32 independent u64 loads/thread = MLP hides MALL latency),
// per-wave s_waitcnt vmcnt(0) + flag release. Two barriers per step.
__global__ __launch_bounds__(256, 1) void k_lstm_layer(
    const float* __restrict__ zx_f, const float* __restrict__ zx_b,
    const float* __restrict__ Whh_f, const float* __restrict__ Whh_b,
    unsigned* __restrict__ hpack, unsigned* __restrict__ hbf,
    unsigned* __restrict__ flags)
{
    int chunk = blockIdx.x;        // 0..15 (32 hidden units each)
    int dir   = blockIdx.y;
    int tid = threadIdx.x;
    int wv = tid >> 6, l = tid & 63;
    int g  = wv;                   // wave = gate
    int lr = l & 15, lk = l >> 4;
    const float* zx  = dir ? zx_b  : zx_f;
    const float* Whh = dir ? Whh_b : Whh_f;
    unsigned* hb = hbf + (size_t)dir * (2*NB*NH);       // [slot][b][k] packed u32
    unsigned* flag = flags + (size_t)dir * (NCHUNK*4);  // dense: [chunk][wave]

    // ---- preload Whh slice: gate g, units chunk*32 + uh*16 + lr, all K ----
    short8v bwh[2][16], bwl[2][16];
    #pragma unroll
    for (int uh = 0; uh < 2; uh++) {
        const float* wrow = Whh + ((size_t)(g*NH + chunk*32 + uh*16 + lr))*NH + lk*8;
        #pragma unroll
        for (int kt = 0; kt < 16; kt++) {
            float u[8];
            *(float4*)&u[0] = *(const float4*)(wrow + kt*32);
            *(float4*)&u[4] = *(const float4*)(wrow + kt*32 + 4);
            short8v sh, sl;
            #pragma unroll
            for (int j = 0; j < 8; j++) {
                short hi = f2bf(u[j]);
                sh[j] = hi;
                sl[j] = f2bf(u[j] - bf2f(hi));
            }
            bwh[uh][kt] = sh; bwl[uh][kt] = sl;
        }
    }

    // LDS: staged h (u64, row stride 258 = 516 u32: 8-lane read groups tile
    // all 32 banks once -> conflict-tame, r6-proven) + zsh handoff
    __shared__ unsigned long long hstage[32*258];   // 66 KB
    __shared__ float zsh[4][32][33];                // 16.9 KB
    float cs0 = 0.f, cs1 = 0.f, cs2 = 0.f, cs3 = 0.f;

    for (int t = 0; t < NS; t++) {
        int t_eff = dir ? (NS-1-t) : t;

        // ---- prefetch zx into regs (independent of the flag) ----
        float pz[4][4];
        #pragma unroll
        for (int cc = 0; cc < 4; cc++) {
            int cell = tid + cc*256, b = cell >> 5, u = cell & 31;
            const float* zr = zx + ((size_t)(b*NS + t_eff))*NG4 + chunk*32 + u;
            #pragma unroll
            for (int g2 = 0; g2 < 4; g2++) pz[cc][g2] = zr[g2*NH];
        }

        if (t > 0) {
            // ---- poll all 64 per-wave flags (2 per lane via u64) ----
            {
                const unsigned long long* fp =
                    (const unsigned long long*)flag + (l & 31);
                unsigned tv = (unsigned)t;
                unsigned long long v;
                do { v = ld64_sc1(fp); }
                while (!__all(((unsigned)v >= tv) && ((unsigned)(v>>32) >= tv)));
                asm volatile("" ::: "memory");
            }
            // ---- burst stage: 32 independent coalesced u64 sc1 loads/thread ----
            const unsigned long long* hp64 =
                (const unsigned long long*)(hb + ((t-1)&1)*(NB*NH));
            unsigned long long sv[32];
            #pragma unroll
            for (int i = 0; i < 32; i++) sv[i] = ld64_sc1(hp64 + i*256 + tid);
            #pragma unroll
            for (int i = 0; i < 32; i++) hstage[i*258 + tid] = sv[i];
        }
        __syncthreads();   // barrier A: stage visible

        // accumulators: [bh][uh] main + cross (merged al*wh + ah*wl chains)
        f32x4 am00={0,0,0,0}, am01={0,0,0,0}, am10={0,0,0,0}, am11={0,0,0,0};
        f32x4 ac00={0,0,0,0}, ac01={0,0,0,0}, ac10={0,0,0,0}, ac11={0,0,0,0};
        if (t > 0) {
            #pragma unroll
            for (int kt = 0; kt < 16; kt++) {
                short8v ah0, al0, ah1, al1;
                {
                    unsigned w8[8];
                    const unsigned long long* sp0 = &hstage[(size_t)lr*258 + kt*16 + lk*4];
                    const unsigned long long* sp1 = &hstage[(size_t)(16+lr)*258 + kt*16 + lk*4];
                    unsigned long long q0 = sp0[0], q1 = sp0[1], q2 = sp0[2], q3 = sp0[3];
                    w8[0]=(unsigned)q0; w8[1]=(unsigned)(q0>>32);
                    w8[2]=(unsigned)q1; w8[3]=(unsigned)(q1>>32);
                    w8[4]=(unsigned)q2; w8[5]=(unsigned)(q2>>32);
                    w8[6]=(unsigned)q3; w8[7]=(unsigned)(q3>>32);
                    unpack8(w8, ah0, al0);
                    q0 = sp1[0]; q1 = sp1[1]; q2 = sp1[2]; q3 = sp1[3];
                    w8[0]=(unsigned)q0; w8[1]=(unsigned)(q0>>32);
                    w8[2]=(unsigned)q1; w8[3]=(unsigned)(q1>>32);
                    w8[4]=(unsigned)q2; w8[5]=(unsigned)(q2>>32);
                    w8[6]=(unsigned)q3; w8[7]=(unsigned)(q3>>32);
                    unpack8(w8, ah1, al1);
                }
                am00 = __builtin_amdgcn_mfma_f32_16x16x32_bf16(ah0, bwh[0][kt], am00, 0, 0, 0);
                am01 = __builtin_amdgcn_mfma_f32_16x16x32_bf16(ah0, bwh[1][kt], am01, 0, 0, 0);
                am10 = __builtin_amdgcn_mfma_f32_16x16x32_bf16(ah1, bwh[0][kt], am10, 0, 0, 0);
                am11 = __builtin_amdgcn_mfma_f32_16x16x32_bf16(ah1, bwh[1][kt], am11, 0, 0, 0);
                ac00 = __builtin_amdgcn_mfma_f32_16x16x32_bf16(al0, bwh[0][kt], ac00, 0, 0, 0);
                ac00 = __builtin_amdgcn_mfma_f32_16x16x32_bf16(ah0, bwl[0][kt], ac00, 0, 0, 0);
                ac01 = __builtin_amdgcn_mfma_f32_16x16x32_bf16(al0, bwh[1][kt], ac01, 0, 0, 0);
                ac01 = __builtin_amdgcn_mfma_f32_16x16x32_bf16(ah0, bwl[1][kt], ac01, 0, 0, 0);
                ac10 = __builtin_amdgcn_mfma_f32_16x16x32_bf16(al1, bwh[0][kt], ac10, 0, 0, 0);
                ac10 = __builtin_amdgcn_mfma_f32_16x16x32_bf16(ah1, bwl[0][kt], ac10, 0, 0, 0);
                ac11 = __builtin_amdgcn_mfma_f32_16x16x32_bf16(al1, bwh[1][kt], ac11, 0, 0, 0);
                ac11 = __builtin_amdgcn_mfma_f32_16x16x32_bf16(ah1, bwl[1][kt], ac11, 0, 0, 0);
            }
        }
        // C layout: col=lane&15 -> unit uh*16+lr, row=(lane>>4)*4+j -> batch
        #pragma unroll
        for (int j = 0; j < 4; j++) {
            zsh[g][lk*4+j][lr]       = am00[j] + ac00[j];
            zsh[g][lk*4+j][16+lr]    = am01[j] + ac01[j];
            zsh[g][16+lk*4+j][lr]    = am10[j] + ac10[j];
            zsh[g][16+lk*4+j][16+lr] = am11[j] + ac11[j];
        }
        __syncthreads();   // barrier B: zsh ready

        // ---- epilogue: 1024 cells / 256 threads (4 each) ----
        unsigned hq[4];
        #pragma unroll
        for (int cc = 0; cc < 4; cc++) {
            int cell = tid + cc*256, b = cell >> 5, u = cell & 31;
            float zi = pz[cc][0] + zsh[0][b][u];
            float zf = pz[cc][1] + zsh[1][b][u];
            float zg = pz[cc][2] + zsh[2][b][u];
            float zo = pz[cc][3] + zsh[3][b][u];
            float cold = (cc==0) ? cs0 : (cc==1) ? cs1 : (cc==2) ? cs2 : cs3;
            float cn = sigmoidf_(zf)*cold + sigmoidf_(zi)*tanhf(zg);
            float hn = sigmoidf_(zo)*tanhf(cn);
            if (cc==0) cs0 = cn; else if (cc==1) cs1 = cn; else if (cc==2) cs2 = cn; else cs3 = cn;
            hq[cc] = packbf3(hn);
            st_sc1(&hb[(size_t)(t&1)*(NB*NH) + b*NH + chunk*32 + u], hq[cc]);
        }
        // per-wave release: own stores acked at MALL, then own flag
        asm volatile("s_waitcnt vmcnt(0)" ::: "memory");
        if (l == 0) st_sc1(&flag[chunk*4 + wv], (unsigned)(t+1));
        // packed h for downstream GEMMs (off critical path)
        #pragma unroll
        for (int cc = 0; cc < 4; cc++) {
            int cell = tid + cc*256, b = cell >> 5, u = cell & 31;
            hpack[((size_t)(b*NS + t_eff))*NIN1 + dir*NH + chunk*32 + u] = hq[cc];
        }
    }
}

// ---------------- emissions: em = hid1 @ lin2W^T + b2 ----------------
__global__ __launch_bounds__(256) void k_lin2(const float* __restrict__ hid,
    const float* __restrict__ W2, const float* __restrict__ b2, float* __restrict__ em)
{
    int flat = blockIdx.x*256 + threadIdx.x;
    if (flat >= NBS*NT) return;
    int m = flat / NT, j = flat % NT;
    const float* hr = hid + (size_t)m*NHID;
    const float* wr = W2 + j*NHID;
    float acc = b2[j];
    #pragma unroll 8
    for (int k = 0; k < NHID; k += 4) {
        float4 h4 = *(const float4*)(hr+k);
        float4 w4 = *(const float4*)(wr+k);
        acc += h4.x*w4.x + h4.y*w4.y + h4.z*w4.z + h4.w*w4.w;
    }
    em[flat] = acc;
}

// ---------------- viterbi decode (one wave per batch item) ----------------
__global__ __launch_bounds__(64) void k_viterbi(const float* __restrict__ em,
    const float* __restrict__ start, const float* __restrict__ endv,
    const float* __restrict__ trans, float* __restrict__ dec)
{
    __shared__ float sc[NT];
    __shared__ float tr[NT][NT];
    __shared__ unsigned char hist[NS][NT];
    int b = blockIdx.x, tid = threadIdx.x;
    for (int i = tid; i < NT*NT; i += 64) tr[i/NT][i%NT] = trans[i];
    if (tid < NT) sc[tid] = start[tid] + em[((size_t)b*NS)*NT + tid];
    __syncthreads();
    for (int t = 1; t < NS; t++) {
        float best = -1e30f; int bi = 0;
        if (tid < NT) {
            for (int i = 0; i < NT; i++) {
                float v = sc[i] + tr[i][tid];
                if (v > best) { best = v; bi = i; }
            }
            hist[t][tid] = (unsigned char)bi;
            best += em[((size_t)b*NS + t)*NT + tid];
        }
        __syncthreads();
        if (tid < NT) sc[tid] = best;
        __syncthreads();
    }
    if (tid == 0) {
        float bv = sc[0] + endv[0]; int tag = 0;
        for (int j = 1; j < NT; j++) { float v = sc[j] + endv[j]; if (v > bv) { bv = v; tag = j; } }
        dec[b*NS + NS-1] = (float)tag;
        for (int t = NS-1; t >= 1; t--) { tag = hist[t][tag]; dec[b*NS + t-1] = (float)tag; }
    }
}

// ---------------- CRF NLL (mask is all ones) ----------------
__global__ __launch_bounds__(64) void k_nll(const float* __restrict__ em,
    const int* __restrict__ tags, const float* __restrict__ start,
    const float* __restrict__ endv, const float* __restrict__ trans,
    float* __restrict__ partial)
{
    __shared__ float sc[NT];
    __shared__ float tr[NT][NT];
    int b = blockIdx.x, tid = threadIdx.x;
    for (int i = tid; i < NT*NT; i += 64) tr[i/NT][i%NT] = trans[i];
    if (tid < NT) sc[tid] = start[tid] + em[((size_t)b*NS)*NT + tid];
    __syncthreads();
    for (int t = 1; t < NS; t++) {
        float nv = 0.f;
        if (tid < NT) {
            float m = -1e30f;
            for (int i = 0; i < NT; i++) m = fmaxf(m, sc[i] + tr[i][tid]);
            float s = 0.f;
            for (int i = 0; i < NT; i++) s += expf(sc[i] + tr[i][tid] - m);
            nv = m + logf(s) + em[((size_t)b*NS + t)*NT + tid];
        }
        __syncthreads();
        if (tid < NT) sc[tid] = nv;
        __syncthreads();
    }
    if (tid == 0) {
        float m = -1e30f;
        for (int j = 0; j < NT; j++) m = fmaxf(m, sc[j] + endv[j]);
        float s = 0.f;
        for (int j = 0; j < NT; j++) s += expf(sc[j] + endv[j] - m);
        float logZ = m + logf(s);
        const int* tg = tags + b*NS;
        float num = start[tg[0]] + em[((size_t)b*NS)*NT + tg[0]];
        for (int t = 1; t < NS; t++)
            num += tr[tg[t-1]][tg[t]] + em[((size_t)b*NS + t)*NT + tg[t]];
        num += endv[tg[NS-1]];
        partial[b] = -(num - logZ);
    }
}

__global__ void k_loss_final(const float* __restrict__ partial, float* __restrict__ loss)
{
    if (threadIdx.x == 0 && blockIdx.x == 0) {
        float s = 0.f;
        for (int b = 0; b < NB; b++) s += partial[b];
        *loss = s / (float)(NB*NS);
    }
}

extern "C" void kernel_launch(void* const* d_in, const int* in_sizes, int n_in,
                              void* d_out, int out_size, void* d_ws, size_t ws_size,
                              hipStream_t stream)
{
    const int*   x_word = (const int*)d_in[0];
    const float* x_pos  = (const float*)d_in[1];
    const int*   x_char = (const int*)d_in[2];
    const float* x_enr  = (const float*)d_in[3];
    const int*   y_word = (const int*)d_in[5];
    const float* wembW  = (const float*)d_in[6];
    const float* cembW  = (const float*)d_in[7];
    const float* cnnW   = (const float*)d_in[8];
    const float* cnnb   = (const float*)d_in[9];
    const float* lin1W  = (const float*)d_in[10];
    const float* lin1b  = (const float*)d_in[11];
    const float* lin2W  = (const float*)d_in[12];
    const float* lin2b  = (const float*)d_in[13];
    const float* crf_s  = (const float*)d_in[14];
    const float* crf_e  = (const float*)d_in[15];
    const float* crf_tr = (const float*)d_in[16];
    const float* l0f_Wih = (const float*)d_in[17];
    const float* l0f_Whh = (const float*)d_in[18];
    const float* l0f_b   = (const float*)d_in[19];
    const float* l0b_Wih = (const float*)d_in[20];
    const float* l0b_Whh = (const float*)d_in[21];
    const float* l0b_b   = (const float*)d_in[22];
    const float* l1f_Wih = (const float*)d_in[23];
    const float* l1f_Whh = (const float*)d_in[24];
    const float* l1f_b   = (const float*)d_in[25];
    const float* l1b_Wih = (const float*)d_in[26];
    const float* l1b_Whh = (const float*)d_in[27];
    const float* l1b_b   = (const float*)d_in[28];

    unsigned* ws = (unsigned*)d_ws;
    size_t off = 0;
    unsigned* xwp  = ws + off; off += (size_t)NBS*NIN0P;
    unsigned* w0fp = ws + off; off += (size_t)NG4*NIN0P;
    unsigned* w0bp = ws + off; off += (size_t)NG4*NIN0P;
    unsigned* w1fp = ws + off; off += (size_t)NG4*NIN1;
    unsigned* w1bp = ws + off; off += (size_t)NG4*NIN1;
    unsigned* wl1p = ws + off; off += (size_t)NHID*NIN1;
    float*    zxf  = (float*)(ws + off); off += (size_t)NBS*NG4;
    float*    zxb  = (float*)(ws + off); off += (size_t)NBS*NG4;
    unsigned* h0p  = ws + off; off += (size_t)NBS*NIN1;
    unsigned* h1p  = ws + off; off += (size_t)NBS*NIN1;
    float*    hid1 = (float*)(ws + off); off += (size_t)NBS*NHID;
    float*    partial = (float*)(ws + off); off += 64;
    unsigned* hbf  = ws + off; off += (size_t)2*2*NB*NH;
    unsigned* flags= ws + off; off += (size_t)2*NCHUNK*4;

    float* em_out   = (float*)d_out;
    float* dec_out  = em_out + (size_t)NBS*NT;
    float* loss_out = dec_out + NBS;

    // 1. pack weights
    k_pack_w<<<(NG4*NIN0P+255)/256, 256, 0, stream>>>(l0f_Wih, w0fp, NG4, NIN0, NIN0P);
    k_pack_w<<<(NG4*NIN0P+255)/256, 256, 0, stream>>>(l0b_Wih, w0bp, NG4, NIN0, NIN0P);
    k_pack_w<<<(NG4*NIN1+255)/256, 256, 0, stream>>>(l1f_Wih, w1fp, NG4, NIN1, NIN1);
    k_pack_w<<<(NG4*NIN1+255)/256, 256, 0, stream>>>(l1b_Wih, w1bp, NG4, NIN1, NIN1);
    k_pack_w<<<(NHID*NIN1+255)/256, 256, 0, stream>>>(lin1W, wl1p, NHID, NIN1, NIN1);
    // 2. features (packed)
    k_features<<<NBS, 128, 0, stream>>>(x_word, x_pos, x_char, x_enr, wembW, cembW, cnnW, cnnb, xwp);
    // 3. layer-0 input projections
    k_gemm_bf3<<<dim3(NBS/128, NG4/128), 256, 0, stream>>>(xwp, w0fp, l0f_b, zxf, NBS, NG4, NIN0P);
    k_gemm_bf3<<<dim3(NBS/128, NG4/128), 256, 0, stream>>>(xwp, w0bp, l0b_b, zxb, NBS, NG4, NIN0P);
    // 4. layer-0 recurrence
    hipMemsetAsync(flags, 0, (size_t)2*NCHUNK*4*sizeof(unsigned), stream);
    k_lstm_layer<<<dim3(NCHUNK, 2), 256, 0, stream>>>(zxf, zxb, l0f_Whh, l0b_Whh, h0p, hbf, flags);
    // 5. layer-1 input projections
    k_gemm_bf3<<<dim3(NBS/128, NG4/128), 256, 0, stream>>>(h0p, w1fp, l1f_b, zxf, NBS, NG4, NIN1);
    k_gemm_bf3<<<dim3(NBS/128, NG4/128), 256, 0, stream>>>(h0p, w1bp, l1b_b, zxb, NBS, NG4, NIN1);
    // 6. layer-1 recurrence
    hipMemsetAsync(flags, 0, (size_t)2*NCHUNK*4*sizeof(unsigned), stream);
    k_lstm_layer<<<dim3(NCHUNK, 2), 256, 0, stream>>>(zxf, zxb, l1f_Whh, l1b_Whh, h1p, hbf, flags);
    // 7. head
    k_gemm_bf3<<<dim3(NBS/128, NHID/128), 256, 0, stream>>>(h1p, wl1p, lin1b, hid1, NBS, NHID, NIN1);
    k_lin2<<<(NBS*NT+255)/256, 256, 0, stream>>>(hid1, lin2W, lin2b, em_out);
    // 8. CRF
    k_viterbi<<<NB, 64, 0, stream>>>(em_out, crf_s, crf_e, crf_tr, dec_out);
    k_nll<<<NB, 64, 0, stream>>>(em_out, y_word, crf_s, crf_e, crf_tr, partial);
    k_loss_final<<<1, 64, 0, stream>>>(partial, loss_out);
}

// Round 9
// 6214.267 us; speedup vs baseline: 2.1032x; 1.0579x over previous
//
#include <hip/hip_runtime.h>
#include <hip/hip_bf16.h>
#include <math.h>

// ---- problem dims ----
constexpr int NB   = 32;
constexpr int NS   = 256;
constexpr int NLC  = 16;
constexpr int NWD  = 256;
constexpr int NCD  = 124;
constexpr int NCO  = 32;
constexpr int NPOS = 36;
constexpr int NENR = 7;
constexpr int NH   = 512;
constexpr int NT   = 18;
constexpr int NIN0 = 331;
constexpr int NIN0P= 352;    // padded to x32 for BK=32
constexpr int NIN1 = 1024;
constexpr int NBS  = NB*NS;  // 8192
constexpr int NG4  = 4*NH;   // 2048
constexpr int NHID = 128;
constexpr int NCHUNK = 16;   // unit-chunks per dir (32 units each)

typedef __attribute__((ext_vector_type(8))) short short8v;
typedef __attribute__((ext_vector_type(4))) float f32x4;

__device__ __forceinline__ float sigmoidf_(float x){ return 1.0f/(1.0f+expf(-x)); }
__device__ __forceinline__ short f2bf(float f) {
    union { __hip_bfloat16 h; short s; } u;
    u.h = __float2bfloat16(f);
    return u.s;
}
__device__ __forceinline__ float bf2f(short s) {
    union { unsigned u; float f; } v;
    v.u = ((unsigned)(unsigned short)s) << 16;
    return v.f;
}
__device__ __forceinline__ unsigned packbf3(float v) {
    short hi = f2bf(v);
    short lo = f2bf(v - bf2f(hi));
    return ((unsigned)(unsigned short)hi << 16) | (unsigned short)lo;
}
// 8 packed u32 (elems k..k+7) -> hi/lo bf16 fragments
__device__ __forceinline__ void unpack8(const unsigned* w, short8v& hi, short8v& lo) {
    union U { short8v s; unsigned u[4]; } H, L;
    #pragma unroll
    for (int i = 0; i < 4; i++) {
        H.u[i] = (w[2*i+1] & 0xFFFF0000u) | (w[2*i] >> 16);
        L.u[i] = (w[2*i+1] << 16) | (w[2*i] & 0xFFFFu);
    }
    hi = H.s; lo = L.s;
}
// relaxed agent-scope ops (sc1 path, no cache maintenance) — proven in r6
__device__ __forceinline__ unsigned ld_sc1(const unsigned* p) {
    return __hip_atomic_load(p, __ATOMIC_RELAXED, __HIP_MEMORY_SCOPE_AGENT);
}
__device__ __forceinline__ unsigned long long ld64_sc1(const void* p) {
    return __hip_atomic_load((const unsigned long long*)p, __ATOMIC_RELAXED,
                             __HIP_MEMORY_SCOPE_AGENT);
}
__device__ __forceinline__ void st_sc1(unsigned* p, unsigned v) {
    __hip_atomic_store(p, v, __ATOMIC_RELAXED, __HIP_MEMORY_SCOPE_AGENT);
}

// ---------------- features: word embed + char CNN + concat + relu -> packed u32 ----
__global__ __launch_bounds__(128) void k_features(const int* __restrict__ x_word,
    const float* __restrict__ x_pos, const int* __restrict__ x_char,
    const float* __restrict__ x_enr, const float* __restrict__ wembW,
    const float* __restrict__ cembW, const float* __restrict__ cnnW,
    const float* __restrict__ cnnb, unsigned* __restrict__ xout)
{
    __shared__ float ce[NLC][NCD];
    __shared__ float cv[NCO][13];
    __shared__ float cpool[NCO];
    int n = blockIdx.x;
    int tid = threadIdx.x;
    for (int i = tid; i < NLC*NCD; i += 128) {
        int l = i / NCD, c = i % NCD;
        ce[l][c] = cembW[x_char[n*NLC + l]*NCD + c];
    }
    __syncthreads();
    for (int p = tid; p < NCO*12; p += 128) {
        int o = p & 31, t = p >> 5;
        const float* wr = cnnW + o*NCD*5;
        float acc = 0.f;
        for (int c = 0; c < NCD; c++) {
            #pragma unroll
            for (int k = 0; k < 5; k++) acc += ce[t+k][c] * wr[c*5+k];
        }
        cv[o][t] = acc;
    }
    __syncthreads();
    if (tid < NCO) {
        float m = cv[tid][0];
        #pragma unroll
        for (int t = 1; t < 12; t++) m = fmaxf(m, cv[tid][t]);
        cpool[tid] = m + cnnb[tid];
    }
    __syncthreads();
    int widx = x_word[n];
    unsigned* xr = xout + (size_t)n * NIN0P;
    for (int j = tid; j < NIN0P; j += 128) {
        float v;
        if (j < NWD)            v = wembW[(size_t)widx*NWD + j];
        else if (j < NWD+NPOS)  v = x_pos[n*NPOS + (j-NWD)];
        else if (j < NWD+NPOS+NCO) v = cpool[j-(NWD+NPOS)];
        else if (j < NIN0)      v = x_enr[n*NENR + (j-(NWD+NPOS+NCO))];
        else                    v = 0.f;   // K pad
        xr[j] = packbf3(fmaxf(v, 0.f));
    }
}

// ---------------- pack f32 weight [N][Ksrc] -> packed u32 [N][Kdst] (zero pad) ----
__global__ void k_pack_w(const float* __restrict__ W, unsigned* __restrict__ out,
                         int N, int Ksrc, int Kdst)
{
    int idx = blockIdx.x*256 + threadIdx.x;
    if (idx >= N*Kdst) return;
    int n = idx / Kdst, k = idx % Kdst;
    float v = (k < Ksrc) ? W[(size_t)n*Ksrc + k] : 0.f;
    out[idx] = packbf3(v);
}

// ---------------- bf16x3 MFMA GEMM: C[M,N] = A@W^T + bias ----------------
constexpr int TBK = 32;
constexpr int LSTR = 36;
__global__ __launch_bounds__(256, 2) void k_gemm_bf3(
    const unsigned* __restrict__ A, const unsigned* __restrict__ W,
    const float* __restrict__ bias, float* __restrict__ C,
    int M, int N, int K)
{
    __shared__ unsigned Asl[128*LSTR];
    __shared__ unsigned Bsl[128*LSTR];
    int bm = blockIdx.x*128, bn = blockIdx.y*128;
    int tid = threadIdx.x;
    int l = tid & 63, wv = tid >> 6;
    int wm = wv >> 1, wn = wv & 1;
    int lr = l & 15, lk = l >> 4;

    f32x4 acc[4][4];
    #pragma unroll
    for (int i = 0; i < 4; i++)
        #pragma unroll
        for (int j = 0; j < 4; j++) acc[i][j] = (f32x4){0.f,0.f,0.f,0.f};

    uint4 ra[4], rb[4];
    int KT = K / TBK;
    #pragma unroll
    for (int i = 0; i < 4; i++) {
        int idx = i*256 + tid, row = idx >> 3, c4 = (idx & 7)*4;
        ra[i] = *(const uint4*)(A + (size_t)(bm+row)*K + c4);
        rb[i] = *(const uint4*)(W + (size_t)(bn+row)*K + c4);
    }
    for (int kt = 0; kt < KT; kt++) {
        #pragma unroll
        for (int i = 0; i < 4; i++) {
            int idx = i*256 + tid, row = idx >> 3, c4 = (idx & 7)*4;
            *(uint4*)&Asl[row*LSTR + c4] = ra[i];
            *(uint4*)&Bsl[row*LSTR + c4] = rb[i];
        }
        __syncthreads();
        if (kt+1 < KT) {
            #pragma unroll
            for (int i = 0; i < 4; i++) {
                int idx = i*256 + tid, row = idx >> 3, c4 = (idx & 7)*4;
                ra[i] = *(const uint4*)(A + (size_t)(bm+row)*K + (kt+1)*TBK + c4);
                rb[i] = *(const uint4*)(W + (size_t)(bn+row)*K + (kt+1)*TBK + c4);
            }
        }
        short8v Ah[4], Al_[4], Bh[4], Bl[4];
        #pragma unroll
        for (int f = 0; f < 4; f++) {
            unsigned w8[8];
            int rowA = wm*64 + f*16 + lr;
            *(uint4*)&w8[0] = *(const uint4*)&Asl[rowA*LSTR + lk*8];
            *(uint4*)&w8[4] = *(const uint4*)&Asl[rowA*LSTR + lk*8 + 4];
            unpack8(w8, Ah[f], Al_[f]);
            int rowB = wn*64 + f*16 + lr;
            *(uint4*)&w8[0] = *(const uint4*)&Bsl[rowB*LSTR + lk*8];
            *(uint4*)&w8[4] = *(const uint4*)&Bsl[rowB*LSTR + lk*8 + 4];
            unpack8(w8, Bh[f], Bl[f]);
        }
        #pragma unroll
        for (int i = 0; i < 4; i++)
            #pragma unroll
            for (int j = 0; j < 4; j++) {
                acc[i][j] = __builtin_amdgcn_mfma_f32_16x16x32_bf16(Ah[i],  Bh[j], acc[i][j], 0, 0, 0);
                acc[i][j] = __builtin_amdgcn_mfma_f32_16x16x32_bf16(Al_[i], Bh[j], acc[i][j], 0, 0, 0);
                acc[i][j] = __builtin_amdgcn_mfma_f32_16x16x32_bf16(Ah[i],  Bl[j], acc[i][j], 0, 0, 0);
            }
        __syncthreads();
    }
    #pragma unroll
    for (int i = 0; i < 4; i++) {
        int m0 = bm + wm*64 + i*16 + lk*4;
        #pragma unroll
        for (int j = 0; j < 4; j++) {
            int n0 = bn + wn*64 + j*16 + lr;
            float bv = bias[n0];
            #pragma unroll
            for (int q = 0; q < 4; q++)
                C[(size_t)(m0+q)*N + n0] = acc[i][j][q] + bv;
        }
    }
}

// ---------------- persistent LSTM layer: 16 chunks x 2 dirs, 512 thr ----------
// r6's proven 8-wave split-K structure (2 waves/SIMD TLP + 64-VGPR weights) with:
//  - XOR-swizzled u64 hstage (col ^ ((row&7)<<2)) -> conflict-free MFMA ds_reads
//  - u64 burst staging (16 loads/thread)
//  - per-wave dense flags + per-wave vmcnt(0) release (barrier C deleted)
// Exchange discipline (r6-proven): relaxed agent-scope (sc1) only.
__global__ __launch_bounds__(512, 2) void k_lstm_layer(
    const float* __restrict__ zx_f, const float* __restrict__ zx_b,
    const float* __restrict__ Whh_f, const float* __restrict__ Whh_b,
    unsigned* __restrict__ hpack, unsigned* __restrict__ hbf,
    unsigned* __restrict__ flags)
{
    int chunk = blockIdx.x;        // 0..15 (32 hidden units each)
    int dir   = blockIdx.y;
    int tid = threadIdx.x;
    int wv = tid >> 6, l = tid & 63;
    int g  = wv & 3;               // gate
    int ks = wv >> 2;              // K-half (0/1)
    int lr = l & 15, lk = l >> 4;
    const float* zx  = dir ? zx_b  : zx_f;
    const float* Whh = dir ? Whh_b : Whh_f;
    unsigned* hb = hbf + (size_t)dir * (2*NB*NH);        // [slot][b][k] packed u32
    unsigned* flag = flags + (size_t)dir * (NCHUNK*8);   // dense [chunk][wave]

    // ---- preload Whh slice: gate g, units chunk*32+uh*16+lr, k-half ks ----
    short8v bwh[2][8], bwl[2][8];
    #pragma unroll
    for (int uh = 0; uh < 2; uh++) {
        const float* wrow = Whh + ((size_t)(g*NH + chunk*32 + uh*16 + lr))*NH + ks*256 + lk*8;
        #pragma unroll
        for (int kt = 0; kt < 8; kt++) {
            float u[8];
            *(float4*)&u[0] = *(const float4*)(wrow + kt*32);
            *(float4*)&u[4] = *(const float4*)(wrow + kt*32 + 4);
            short8v sh, sl;
            #pragma unroll
            for (int j = 0; j < 8; j++) {
                short hi = f2bf(u[j]);
                sh[j] = hi;
                sl[j] = f2bf(u[j] - bf2f(hi));
            }
            bwh[uh][kt] = sh; bwl[uh][kt] = sl;
        }
    }

    // swizzled h stage: row-major [32][256] u64, col ^= (row&7)<<2 (64 KB)
    __shared__ unsigned long long hstage[32*256];
    __shared__ float zsh[2][4][32][33];      // [ks][gate][batch][unit] partials
    float c0 = 0.f, c1 = 0.f;

    for (int t = 0; t < NS; t++) {
        int t_eff = dir ? (NS-1-t) : t;

        // ---- prefetch zx (independent of the flag) ----
        float pz[2][4];
        #pragma unroll
        for (int cc = 0; cc < 2; cc++) {
            int cell = tid + cc*512, b = cell >> 5, u = cell & 31;
            const float* zr = zx + ((size_t)(b*NS + t_eff))*NG4 + chunk*32 + u;
            #pragma unroll
            for (int g2 = 0; g2 < 4; g2++) pz[cc][g2] = zr[g2*NH];
        }

        if (t > 0) {
            // ---- poll all 128 per-wave flags (2 per lane via u64) ----
            {
                const unsigned long long* fp =
                    (const unsigned long long*)flag + l;
                unsigned tv = (unsigned)t;
                unsigned long long v;
                do { v = ld64_sc1(fp); }
                while (!__all(((unsigned)v >= tv) && ((unsigned)(v>>32) >= tv)));
                asm volatile("" ::: "memory");
            }
            // ---- burst stage: 16 coalesced u64 sc1 loads/thread -> swizzled LDS ----
            const unsigned long long* hp64 =
                (const unsigned long long*)(hb + ((t-1)&1)*(NB*NH));
            unsigned long long sv[16];
            #pragma unroll
            for (int i = 0; i < 16; i++) sv[i] = ld64_sc1(hp64 + i*512 + tid);
            #pragma unroll
            for (int i = 0; i < 16; i++) {
                int f = i*512 + tid, row = f >> 8, col = f & 255;
                hstage[row*256 + (col ^ ((row&7)<<2))] = sv[i];
            }
        }
        __syncthreads();   // barrier A: stage visible

        // ---- split-K MFMA: wave covers k in [ks*256, ks*256+256) ----
        f32x4 acc[2][2][3];
        #pragma unroll
        for (int bh = 0; bh < 2; bh++)
            #pragma unroll
            for (int uh = 0; uh < 2; uh++)
                #pragma unroll
                for (int q = 0; q < 3; q++) acc[bh][uh][q] = (f32x4){0.f,0.f,0.f,0.f};
        if (t > 0) {
            #pragma unroll
            for (int kt = 0; kt < 8; kt++) {
                short8v ah[2], al[2];
                #pragma unroll
                for (int bh = 0; bh < 2; bh++) {
                    int row = bh*16 + lr;
                    int base = ks*128 + kt*16 + lk*4;
                    const unsigned long long* sp =
                        &hstage[row*256 + (base ^ ((row&7)<<2))];
                    unsigned long long q0 = sp[0], q1 = sp[1], q2 = sp[2], q3 = sp[3];
                    unsigned w8[8];
                    w8[0]=(unsigned)q0; w8[1]=(unsigned)(q0>>32);
                    w8[2]=(unsigned)q1; w8[3]=(unsigned)(q1>>32);
                    w8[4]=(unsigned)q2; w8[5]=(unsigned)(q2>>32);
                    w8[6]=(unsigned)q3; w8[7]=(unsigned)(q3>>32);
                    unpack8(w8, ah[bh], al[bh]);
                }
                #pragma unroll
                for (int bh = 0; bh < 2; bh++)
                    #pragma unroll
                    for (int uh = 0; uh < 2; uh++) {
                        acc[bh][uh][0] = __builtin_amdgcn_mfma_f32_16x16x32_bf16(ah[bh], bwh[uh][kt], acc[bh][uh][0], 0, 0, 0);
                        acc[bh][uh][1] = __builtin_amdgcn_mfma_f32_16x16x32_bf16(al[bh], bwh[uh][kt], acc[bh][uh][1], 0, 0, 0);
                        acc[bh][uh][2] = __builtin_amdgcn_mfma_f32_16x16x32_bf16(ah[bh], bwl[uh][kt], acc[bh][uh][2], 0, 0, 0);
                    }
            }
        }
        // C layout: col=lane&15 -> unit uh*16+lr, row=(lane>>4)*4+j -> batch
        #pragma unroll
        for (int bh = 0; bh < 2; bh++)
            #pragma unroll
            for (int uh = 0; uh < 2; uh++)
                #pragma unroll
                for (int j = 0; j < 4; j++)
                    zsh[ks][g][bh*16 + lk*4 + j][uh*16 + lr] =
                        acc[bh][uh][0][j] + acc[bh][uh][1][j] + acc[bh][uh][2][j];
        __syncthreads();   // barrier B: zsh ready

        // ---- epilogue: 1024 cells / 512 threads (2 each) ----
        unsigned hq0 = 0, hq1 = 0;
        #pragma unroll
        for (int cc = 0; cc < 2; cc++) {
            int cell = tid + cc*512, b = cell >> 5, u = cell & 31;
            float zi = pz[cc][0] + zsh[0][0][b][u] + zsh[1][0][b][u];
            float zf = pz[cc][1] + zsh[0][1][b][u] + zsh[1][1][b][u];
            float zg = pz[cc][2] + zsh[0][2][b][u] + zsh[1][2][b][u];
            float zo = pz[cc][3] + zsh[0][3][b][u] + zsh[1][3][b][u];
            float cold = cc ? c1 : c0;
            float cn = sigmoidf_(zf)*cold + sigmoidf_(zi)*tanhf(zg);
            float hn = sigmoidf_(zo)*tanhf(cn);
            unsigned pk = packbf3(hn);
            if (cc) { c1 = cn; hq1 = pk; } else { c0 = cn; hq0 = pk; }
            st_sc1(&hb[(size_t)(t&1)*(NB*NH) + b*NH + chunk*32 + u], pk);
        }
        // per-wave release: own stores acked at coherence point, then own flag
        asm volatile("s_waitcnt vmcnt(0)" ::: "memory");
        if (l == 0) st_sc1(&flag[chunk*8 + wv], (unsigned)(t+1));
        // packed h for downstream GEMMs (off critical path)
        #pragma unroll
        for (int cc = 0; cc < 2; cc++) {
            int cell = tid + cc*512, b = cell >> 5, u = cell & 31;
            hpack[((size_t)(b*NS + t_eff))*NIN1 + dir*NH + chunk*32 + u] = cc ? hq1 : hq0;
        }
    }
}

// ---------------- emissions: em = hid1 @ lin2W^T + b2 ----------------
__global__ __launch_bounds__(256) void k_lin2(const float* __restrict__ hid,
    const float* __restrict__ W2, const float* __restrict__ b2, float* __restrict__ em)
{
    int flat = blockIdx.x*256 + threadIdx.x;
    if (flat >= NBS*NT) return;
    int m = flat / NT, j = flat % NT;
    const float* hr = hid + (size_t)m*NHID;
    const float* wr = W2 + j*NHID;
    float acc = b2[j];
    #pragma unroll 8
    for (int k = 0; k < NHID; k += 4) {
        float4 h4 = *(const float4*)(hr+k);
        float4 w4 = *(const float4*)(wr+k);
        acc += h4.x*w4.x + h4.y*w4.y + h4.z*w4.z + h4.w*w4.w;
    }
    em[flat] = acc;
}

// ---------------- viterbi decode (one wave per batch item) ----------------
__global__ __launch_bounds__(64) void k_viterbi(const float* __restrict__ em,
    const float* __restrict__ start, const float* __restrict__ endv,
    const float* __restrict__ trans, float* __restrict__ dec)
{
    __shared__ float sc[NT];
    __shared__ float tr[NT][NT];
    __shared__ unsigned char hist[NS][NT];
    int b = blockIdx.x, tid = threadIdx.x;
    for (int i = tid; i < NT*NT; i += 64) tr[i/NT][i%NT] = trans[i];
    if (tid < NT) sc[tid] = start[tid] + em[((size_t)b*NS)*NT + tid];
    __syncthreads();
    for (int t = 1; t < NS; t++) {
        float best = -1e30f; int bi = 0;
        if (tid < NT) {
            for (int i = 0; i < NT; i++) {
                float v = sc[i] + tr[i][tid];
                if (v > best) { best = v; bi = i; }
            }
            hist[t][tid] = (unsigned char)bi;
            best += em[((size_t)b*NS + t)*NT + tid];
        }
        __syncthreads();
        if (tid < NT) sc[tid] = best;
        __syncthreads();
    }
    if (tid == 0) {
        float bv = sc[0] + endv[0]; int tag = 0;
        for (int j = 1; j < NT; j++) { float v = sc[j] + endv[j]; if (v > bv) { bv = v; tag = j; } }
        dec[b*NS + NS-1] = (float)tag;
        for (int t = NS-1; t >= 1; t--) { tag = hist[t][tag]; dec[b*NS + t-1] = (float)tag; }
    }
}

// ---------------- CRF NLL (mask is all ones) ----------------
__global__ __launch_bounds__(64) void k_nll(const float* __restrict__ em,
    const int* __restrict__ tags, const float* __restrict__ start,
    const float* __restrict__ endv, const float* __restrict__ trans,
    float* __restrict__ partial)
{
    __shared__ float sc[NT];
    __shared__ float tr[NT][NT];
    int b = blockIdx.x, tid = threadIdx.x;
    for (int i = tid; i < NT*NT; i += 64) tr[i/NT][i%NT] = trans[i];
    if (tid < NT) sc[tid] = start[tid] + em[((size_t)b*NS)*NT + tid];
    __syncthreads();
    for (int t = 1; t < NS; t++) {
        float nv = 0.f;
        if (tid < NT) {
            float m = -1e30f;
            for (int i = 0; i < NT; i++) m = fmaxf(m, sc[i] + tr[i][tid]);
            float s = 0.f;
            for (int i = 0; i < NT; i++) s += expf(sc[i] + tr[i][tid] - m);
            nv = m + logf(s) + em[((size_t)b*NS + t)*NT + tid];
        }
        __syncthreads();
        if (tid < NT) sc[tid] = nv;
        __syncthreads();
    }
    if (tid == 0) {
        float m = -1e30f;
        for (int j = 0; j < NT; j++) m = fmaxf(m, sc[j] + endv[j]);
        float s = 0.f;
        for (int j = 0; j < NT; j++) s += expf(sc[j] + endv[j] - m);
        float logZ = m + logf(s);
        const int* tg = tags + b*NS;
        float num = start[tg[0]] + em[((size_t)b*NS)*NT + tg[0]];
        for (int t = 1; t < NS; t++)
            num += tr[tg[t-1]][tg[t]] + em[((size_t)b*NS + t)*NT + tg[t]];
        num += endv[tg[NS-1]];
        partial[b] = -(num - logZ);
    }
}

__global__ void k_loss_final(const float* __restrict__ partial, float* __restrict__ loss)
{
    if (threadIdx.x == 0 && blockIdx.x == 0) {
        float s = 0.f;
        for (int b = 0; b < NB; b++) s += partial[b];
        *loss = s / (float)(NB*NS);
    }
}

extern "C" void kernel_launch(void* const* d_in, const int* in_sizes, int n_in,
                              void* d_out, int out_size, void* d_ws, size_t ws_size,
                              hipStream_t stream)
{
    const int*   x_word = (const int*)d_in[0];
    const float* x_pos  = (const float*)d_in[1];
    const int*   x_char = (const int*)d_in[2];
    const float* x_enr  = (const float*)d_in[3];
    const int*   y_word = (const int*)d_in[5];
    const float* wembW  = (const float*)d_in[6];
    const float* cembW  = (const float*)d_in[7];
    const float* cnnW   = (const float*)d_in[8];
    const float* cnnb   = (const float*)d_in[9];
    const float* lin1W  = (const float*)d_in[10];
    const float* lin1b  = (const float*)d_in[11];
    const float* lin2W  = (const float*)d_in[12];
    const float* lin2b  = (const float*)d_in[13];
    const float* crf_s  = (const float*)d_in[14];
    const float* crf_e  = (const float*)d_in[15];
    const float* crf_tr = (const float*)d_in[16];
    const float* l0f_Wih = (const float*)d_in[17];
    const float* l0f_Whh = (const float*)d_in[18];
    const float* l0f_b   = (const float*)d_in[19];
    const float* l0b_Wih = (const float*)d_in[20];
    const float* l0b_Whh = (const float*)d_in[21];
    const float* l0b_b   = (const float*)d_in[22];
    const float* l1f_Wih = (const float*)d_in[23];
    const float* l1f_Whh = (const float*)d_in[24];
    const float* l1f_b   = (const float*)d_in[25];
    const float* l1b_Wih = (const float*)d_in[26];
    const float* l1b_Whh = (const float*)d_in[27];
    const float* l1b_b   = (const float*)d_in[28];

    unsigned* ws = (unsigned*)d_ws;
    size_t off = 0;
    unsigned* xwp  = ws + off; off += (size_t)NBS*NIN0P;
    unsigned* w0fp = ws + off; off += (size_t)NG4*NIN0P;
    unsigned* w0bp = ws + off; off += (size_t)NG4*NIN0P;
    unsigned* w1fp = ws + off; off += (size_t)NG4*NIN1;
    unsigned* w1bp = ws + off; off += (size_t)NG4*NIN1;
    unsigned* wl1p = ws + off; off += (size_t)NHID*NIN1;
    float*    zxf  = (float*)(ws + off); off += (size_t)NBS*NG4;
    float*    zxb  = (float*)(ws + off); off += (size_t)NBS*NG4;
    unsigned* h0p  = ws + off; off += (size_t)NBS*NIN1;
    unsigned* h1p  = ws + off; off += (size_t)NBS*NIN1;
    float*    hid1 = (float*)(ws + off); off += (size_t)NBS*NHID;
    float*    partial = (float*)(ws + off); off += 64;
    unsigned* hbf  = ws + off; off += (size_t)2*2*NB*NH;
    unsigned* flags= ws + off; off += (size_t)2*NCHUNK*8;

    float* em_out   = (float*)d_out;
    float* dec_out  = em_out + (size_t)NBS*NT;
    float* loss_out = dec_out + NBS;

    // 1. pack weights
    k_pack_w<<<(NG4*NIN0P+255)/256, 256, 0, stream>>>(l0f_Wih, w0fp, NG4, NIN0, NIN0P);
    k_pack_w<<<(NG4*NIN0P+255)/256, 256, 0, stream>>>(l0b_Wih, w0bp, NG4, NIN0, NIN0P);
    k_pack_w<<<(NG4*NIN1+255)/256, 256, 0, stream>>>(l1f_Wih, w1fp, NG4, NIN1, NIN1);
    k_pack_w<<<(NG4*NIN1+255)/256, 256, 0, stream>>>(l1b_Wih, w1bp, NG4, NIN1, NIN1);
    k_pack_w<<<(NHID*NIN1+255)/256, 256, 0, stream>>>(lin1W, wl1p, NHID, NIN1, NIN1);
    // 2. features (packed)
    k_features<<<NBS, 128, 0, stream>>>(x_word, x_pos, x_char, x_enr, wembW, cembW, cnnW, cnnb, xwp);
    // 3. layer-0 input projections
    k_gemm_bf3<<<dim3(NBS/128, NG4/128), 256, 0, stream>>>(xwp, w0fp, l0f_b, zxf, NBS, NG4, NIN0P);
    k_gemm_bf3<<<dim3(NBS/128, NG4/128), 256, 0, stream>>>(xwp, w0bp, l0b_b, zxb, NBS, NG4, NIN0P);
    // 4. layer-0 recurrence
    hipMemsetAsync(flags, 0, (size_t)2*NCHUNK*8*sizeof(unsigned), stream);
    k_lstm_layer<<<dim3(NCHUNK, 2), 512, 0, stream>>>(zxf, zxb, l0f_Whh, l0b_Whh, h0p, hbf, flags);
    // 5. layer-1 input projections
    k_gemm_bf3<<<dim3(NBS/128, NG4/128), 256, 0, stream>>>(h0p, w1fp, l1f_b, zxf, NBS, NG4, NIN1);
    k_gemm_bf3<<<dim3(NBS/128, NG4/128), 256, 0, stream>>>(h0p, w1bp, l1b_b, zxb, NBS, NG4, NIN1);
    // 6. layer-1 recurrence
    hipMemsetAsync(flags, 0, (size_t)2*NCHUNK*8*sizeof(unsigned), stream);
    k_lstm_layer<<<dim3(NCHUNK, 2), 512, 0, stream>>>(zxf, zxb, l1f_Whh, l1b_Whh, h1p, hbf, flags);
    // 7. head
    k_gemm_bf3<<<dim3(NBS/128, NHID/128), 256, 0, stream>>>(h1p, wl1p, lin1b, hid1, NBS, NHID, NIN1);
    k_lin2<<<(NBS*NT+255)/256, 256, 0, stream>>>(hid1, lin2W, lin2b, em_out);
    // 8. CRF
    k_viterbi<<<NB, 64, 0, stream>>>(em_out, crf_s, crf_e, crf_tr, dec_out);
    k_nll<<<NB, 64, 0, stream>>>(em_out, y_word, crf_s, crf_e, crf_tr, partial);
    k_loss_final<<<1, 64, 0, stream>>>(partial, loss_out);
}